// Round 4
// baseline (407.661 us; speedup 1.0000x reference)
//
#include <hip/hip_runtime.h>

// RegressionInstancesModule on gfx950 — R4.
// R3 post-mortem: harness re-poison fills (629 MB @ 95 us each) dominate the
// profile and set a ~250 us floor on dur_us. Own-kernel work is ~100-150 us.
// R4: (1) xb gather restructured pixel-fastest (was ic-fastest: 64 lines/wave,
// 150 KB strides); (2) GEMM retiled 64Mx128N — exact 192-row cover (R3 wasted
// 25% of MFMAs in the padded mb=1 tile) and 2 blocks/CU; (3) 6 -> 4 launches
// (prep+xb merged; 1-block fc folded into convc2's idle lanes).

typedef unsigned short bfu;
typedef __attribute__((ext_vector_type(8))) short bf16x8;
typedef __attribute__((ext_vector_type(4))) float f32x4;

__device__ __forceinline__ float bf2f(bfu u) {
  union { unsigned int i; float f; } v;
  v.i = ((unsigned int)u) << 16;
  return v.f;
}
__device__ __forceinline__ bfu f2bf(float f) {
  union { float f; unsigned int i; } v;
  v.f = f;
  unsigned int u = v.i;
  u = (u + 0x7fffu + ((u >> 16) & 1u)) >> 16;
  return (bfu)u;
}

#define B_  4
#define N_  16
#define M_  64
#define H_  480
#define W_  640
#define HF  120
#define WF  160
#define C_  128
#define R_  14
#define PIX 196
#define NE  13
#define KK  1152   // 9*128

// workspace layout (float offsets)
#define WS_XB    0                         // bf16 Xb[64][196][128]
#define WS_XH    802816                    // bf16 Xh[64][196][64]
#define WS_C     1204224                   // f32 c[64][196]
#define WS_GAP   1216768                   // f32 gap[64][128] (sums; zeroed)
#define WS_SCALE 1224960                   // f32 [64]
#define WS_SHIFT 1225024                   // f32 [64]
#define WS_WF    1225088                   // bf16 WF[13][192][1152], k=kidx*128+ic
#define WS_BIASF 2662784                   // f32 [13][192]
#define WS_W2    2665280                   // f32 [13][576], idx=kidx*64+ic
#define WS_B2    2672768                   // f32 [13] (pad 16)
#define WS_WFC   2672784                   // f32 [13][2][128]
#define WS_BFC   2676112                   // f32 [13][2] (pad 32)

#define PREP_BLK 1024

// ------------- prep (blocks 0..1023) + roi->Xb (blocks 1024..1087) -------------
__global__ __launch_bounds__(256) void prep_xb_kernel(
    const float* __restrict__ fmap, const float* __restrict__ boxes,
    const float* __restrict__ w_s, const float* __restrict__ b_s,
    const float* __restrict__ w_fc, const float* __restrict__ b_fc,
    const float* __restrict__ w_c1, const float* __restrict__ b_c1,
    const float* __restrict__ w_c2, const float* __restrict__ b_c2,
    float* __restrict__ ws)
{
  int tid = threadIdx.x;
  if (blockIdx.x < PREP_BLK) {
    const int P0 = NE*192*KK;     // WF bf16
    const int P1 = NE*192;        // biasf
    const int P2 = NE*576;        // w2
    const int P3 = NE;            // b2
    const int P4 = NE*256;        // wfc
    const int P5 = NE*2;          // bfc
    const int P6 = M_*C_;         // gap zero
    int total = P0+P1+P2+P3+P4+P5+P6;
    bfu* wf = (bfu*)(ws + WS_WF);
    for (int idx = blockIdx.x*256 + tid; idx < total; idx += PREP_BLK*256) {
      int d = idx;
      if (d < P0) {
        int e = d / (192*KK);
        int r = d - e*(192*KK);
        int oc = r / KK;
        int k  = r - oc*KK;
        int kidx = k >> 7, ic = k & 127;
        float v = (oc < 128) ? w_s[((e*128 + oc)*128 + ic)*9 + kidx]
                             : w_c1[((e*64 + (oc-128))*128 + ic)*9 + kidx];
        wf[d] = f2bf(v);
        continue;
      }
      d -= P0;
      if (d < P1) {
        int e = d / 192, oc = d - e*192;
        ws[WS_BIASF + d] = (oc < 128) ? b_s[e*128 + oc] : b_c1[e*64 + oc - 128];
        continue;
      }
      d -= P1;
      if (d < P2) {
        int e = d / 576, k = d - e*576;
        int kidx = k >> 6, ic = k & 63;
        ws[WS_W2 + d] = w_c2[(e*64 + ic)*9 + kidx];
        continue;
      }
      d -= P2;
      if (d < P3) { ws[WS_B2 + d] = b_c2[d]; continue; }
      d -= P3;
      if (d < P4) { ws[WS_WFC + d] = w_fc[d]; continue; }
      d -= P4;
      if (d < P5) { ws[WS_BFC + d] = b_fc[d]; continue; }
      d -= P5;
      ws[WS_GAP + d] = 0.f;
    }
    return;
  }

  // ---- ROI-align -> bf16 Xb[m][p][ic], pixel-fastest gather ----
  int m = blockIdx.x - PREP_BLK;
  __shared__ int sy0[PIX], sx0[PIX];
  __shared__ float s00[PIX], s01[PIX], s10[PIX], s11[PIX];
  if (tid < PIX) {
    int p = tid;
    int ry = p / R_, rx = p - ry*R_;
    float by1 = boxes[m*4+0], bx1 = boxes[m*4+1];
    float by2 = boxes[m*4+2], bx2 = boxes[m*4+3];
    float ylo = 0.6f*by1, yhi = ylo + 0.1f + 0.3f*by2;
    float xlo = 0.6f*bx1, xhi = xlo + 0.1f + 0.3f*bx2;
    float ty = ((float)ry + 0.5f) / (float)R_;
    float tx = ((float)rx + 0.5f) / (float)R_;
    float sy = (ylo + (yhi-ylo)*ty) * (float)(HF-1);
    float sx = (xlo + (xhi-xlo)*tx) * (float)(WF-1);
    int y0 = (int)floorf(sy); y0 = y0 < 0 ? 0 : (y0 > HF-2 ? HF-2 : y0);
    int x0 = (int)floorf(sx); x0 = x0 < 0 ? 0 : (x0 > WF-2 ? WF-2 : x0);
    float wy = sy - (float)y0; wy = wy < 0.f ? 0.f : (wy > 1.f ? 1.f : wy);
    float wx = sx - (float)x0; wx = wx < 0.f ? 0.f : (wx > 1.f ? 1.f : wx);
    sy0[p] = y0; sx0[p] = x0;
    s00[p] = (1.f-wy)*(1.f-wx); s01[p] = (1.f-wy)*wx;
    s10[p] = wy*(1.f-wx);       s11[p] = wy*wx;
  }
  __syncthreads();
  if (tid >= PIX) return;
  int p = tid;
  const float* fb = fmap + (size_t)(m / N_) * C_ * HF * WF
                  + (size_t)sy0[p]*WF + sx0[p];
  float w00 = s00[p], w01 = s01[p], w10 = s10[p], w11 = s11[p];
  bfu* xbp = (bfu*)(ws + WS_XB) + ((size_t)m*PIX + p)*128;
  #pragma unroll 2
  for (int icb = 0; icb < 16; ++icb) {
    bfu pk[8];
    #pragma unroll
    for (int u = 0; u < 8; ++u) {
      const float* f = fb + (size_t)(icb*8 + u)*HF*WF;
      float v = f[0]*w00 + f[1]*w01 + f[WF]*w10 + f[WF+1]*w11;
      pk[u] = f2bf(v);
    }
    *(uint4*)&xbp[icb*8] = *(uint4*)pk;
  }
}

// ------- fused GEMM: [192oc x 208pix] = WF x im2col(Xb), 64Mx128N tiles -------
// grid = 64 inst * 3 mb * 2 nb = 384. 4 waves, each 32Mx64N (acc[2][4]).
// mb 0/1 -> hs rows (bias+relu+GAP atomics); mb 2 -> h1 rows (bf16 Xh store).
__global__ __launch_bounds__(256, 2) void gemm_kernel(
    const int* __restrict__ labels, float* __restrict__ ws)
{
  __shared__ bfu lA[64*32];
  __shared__ bfu lB[128*32];
  const bfu* Xb = (const bfu*)(ws + WS_XB);
  const bfu* WFp = (const bfu*)(ws + WS_WF);
  const float* biasf = ws + WS_BIASF;
  float* gap = ws + WS_GAP;
  bfu* Xh = (bfu*)(ws + WS_XH);

  int bx = blockIdx.x;
  int m  = bx / 6;
  int r6 = bx - m*6;
  int mb = r6 >> 1;
  int nb = r6 & 1;
  int e = labels[m];
  int tid = threadIdx.x;
  int wave = tid >> 6, lane = tid & 63;
  int wm = wave >> 1, wn = wave & 1;
  int l15 = lane & 15, q = lane >> 4;

  int arow = tid >> 2, kc = tid & 3;
  const bfu* wr = WFp + (size_t)e*192*KK + (size_t)(mb*64 + arow)*KK + kc*8;
  int aoff = arow*32 + (kc ^ ((arow >> 1) & 3))*8;

  int brow0 = tid >> 2, brow1 = brow0 + 64;
  int boff0 = brow0*32 + (kc ^ ((brow0 >> 1) & 3))*8;
  int boff1 = brow1*32 + (kc ^ ((brow1 >> 1) & 3))*8;
  int pg0 = nb*128 + brow0, pg1 = nb*128 + brow1;
  int py0 = pg0 / 14, px0 = pg0 - py0*14;
  int py1 = pg1 / 14, px1 = pg1 - py1*14;
  bool pv1 = pg1 < PIX;
  const bfu* xbm = Xb + (size_t)m*PIX*128;

  f32x4 acc[2][4];
  #pragma unroll
  for (int i = 0; i < 2; ++i)
    #pragma unroll
    for (int j = 0; j < 4; ++j)
      acc[i][j] = (f32x4){0.f, 0.f, 0.f, 0.f};

  const uint4 z4 = make_uint4(0,0,0,0);
  for (int s = 0; s < 36; ++s) {
    int kidx = s >> 2, icc = s & 3;
    int k3 = kidx / 3;
    int dy = k3 - 1, dx = (kidx - k3*3) - 1;
    uint4 a = *(const uint4*)(wr + s*32);
    int ys0 = py0 + dy, xs0 = px0 + dx;
    int ys1 = py1 + dy, xs1 = px1 + dx;
    bool v0 = (unsigned)ys0 < 14u && (unsigned)xs0 < 14u;
    bool v1 = pv1 && (unsigned)ys1 < 14u && (unsigned)xs1 < 14u;
    uint4 b0 = v0 ? *(const uint4*)(xbm + (size_t)(ys0*14+xs0)*128 + icc*32 + kc*8) : z4;
    uint4 b1 = v1 ? *(const uint4*)(xbm + (size_t)(ys1*14+xs1)*128 + icc*32 + kc*8) : z4;
    __syncthreads();
    *(uint4*)&lA[aoff] = a;
    *(uint4*)&lB[boff0] = b0;
    *(uint4*)&lB[boff1] = b1;
    __syncthreads();
    bf16x8 af[2], bfr[4];
    #pragma unroll
    for (int i = 0; i < 2; ++i) {
      int rr = wm*32 + i*16 + l15;
      af[i] = *(const bf16x8*)&lA[rr*32 + (q ^ ((rr >> 1) & 3))*8];
    }
    #pragma unroll
    for (int j = 0; j < 4; ++j) {
      int rr = wn*64 + j*16 + l15;
      bfr[j] = *(const bf16x8*)&lB[rr*32 + (q ^ ((rr >> 1) & 3))*8];
    }
    #pragma unroll
    for (int i = 0; i < 2; ++i)
      #pragma unroll
      for (int j = 0; j < 4; ++j)
        acc[i][j] = __builtin_amdgcn_mfma_f32_16x16x32_bf16(af[i], bfr[j], acc[i][j], 0, 0, 0);
  }

  if (mb < 2) {
    // hs rows: bias + relu, masked pixel-sum, atomic into gap
    #pragma unroll
    for (int i = 0; i < 2; ++i) {
      int ocb = mb*64 + wm*32 + i*16 + q*4;
      f32x4 bv = *(const f32x4*)&biasf[e*192 + ocb];
      #pragma unroll
      for (int rr = 0; rr < 4; ++rr) {
        float sum = 0.f;
        #pragma unroll
        for (int j = 0; j < 4; ++j) {
          int p = nb*128 + wn*64 + j*16 + l15;
          float v = acc[i][j][rr] + bv[rr];
          v = v > 0.f ? v : 0.f;
          if (p < PIX) sum += v;
        }
        sum += __shfl_xor(sum, 1);
        sum += __shfl_xor(sum, 2);
        sum += __shfl_xor(sum, 4);
        sum += __shfl_xor(sum, 8);
        if (l15 == 0) atomicAdd(&gap[m*C_ + ocb + rr], sum);
      }
    }
  } else {
    // h1 rows (ic = oc-128): bias + relu, bf16 store to Xh[m][p][ic]
    #pragma unroll
    for (int i = 0; i < 2; ++i) {
      int icb = wm*32 + i*16 + q*4;
      f32x4 bv = *(const f32x4*)&biasf[e*192 + 128 + icb];
      #pragma unroll
      for (int j = 0; j < 4; ++j) {
        int p = nb*128 + wn*64 + j*16 + l15;
        if (p < PIX) {
          ushort4 pk;
          float v0 = acc[i][j][0] + bv[0]; v0 = v0 > 0.f ? v0 : 0.f;
          float v1 = acc[i][j][1] + bv[1]; v1 = v1 > 0.f ? v1 : 0.f;
          float v2 = acc[i][j][2] + bv[2]; v2 = v2 > 0.f ? v2 : 0.f;
          float v3 = acc[i][j][3] + bv[3]; v3 = v3 > 0.f ? v3 : 0.f;
          pk.x = f2bf(v0); pk.y = f2bf(v1); pk.z = f2bf(v2); pk.w = f2bf(v3);
          *(ushort4*)&Xh[((size_t)m*PIX + p)*64 + icb] = pk;
        }
      }
    }
  }
}

// --------- conv_c2 (3x3, 64ch -> 1) + FC (scale/shift) in idle lanes ---------
__global__ __launch_bounds__(256) void convc2_fc_kernel(
    const int* __restrict__ labels, float* __restrict__ ws,
    float* __restrict__ out)
{
  __shared__ bfu xh[PIX*64];
  __shared__ float w2l[576];
  int m = blockIdx.x;
  int e = labels[m];
  int tid = threadIdx.x;
  const bfu* Xh = (const bfu*)(ws + WS_XH) + (size_t)m*PIX*64;
  for (int i = tid; i < PIX*64/8; i += 256)
    *(uint4*)&xh[i*8] = *(const uint4*)&Xh[i*8];
  for (int i = tid; i < 576; i += 256)
    w2l[i] = ws[WS_W2 + e*576 + i];
  __syncthreads();
  if (tid < PIX) {
    int y = tid / 14, x = tid - (tid/14)*14;
    float acc = 0.f;
    #pragma unroll
    for (int kidx = 0; kidx < 9; ++kidx) {
      int ys = y + kidx/3 - 1, xs = x + (kidx - (kidx/3)*3) - 1;
      if ((unsigned)ys < 14u && (unsigned)xs < 14u) {
        const bfu* xr = xh + (ys*14 + xs)*64;
        const float* wr = w2l + kidx*64;
        #pragma unroll
        for (int cc = 0; cc < 8; ++cc) {
          bf16x8 xv = *(const bf16x8*)&xr[cc*8];
          f32x4 wa = *(const f32x4*)&wr[cc*8];
          f32x4 wb = *(const f32x4*)&wr[cc*8 + 4];
          acc += bf2f((bfu)xv[0])*wa[0] + bf2f((bfu)xv[1])*wa[1]
               + bf2f((bfu)xv[2])*wa[2] + bf2f((bfu)xv[3])*wa[3]
               + bf2f((bfu)xv[4])*wb[0] + bf2f((bfu)xv[5])*wb[1]
               + bf2f((bfu)xv[6])*wb[2] + bf2f((bfu)xv[7])*wb[3];
        }
      }
    }
    ws[WS_C + m*PIX + tid] = acc + ws[WS_B2 + e];
  } else if (tid >= 208 && tid < 240) {
    // FC: tid 208-223 (lanes 16-31 of wave 3) -> o=0; 224-239 (lanes 32-47) -> o=1
    int o = (tid - 208) >> 4;
    int g16 = (tid - 208) & 15;
    const float* g = ws + WS_GAP + m*C_ + g16*8;
    const float* wv = ws + WS_WFC + (e*2 + o)*C_ + g16*8;
    float s = 0.f;
    #pragma unroll
    for (int c = 0; c < 8; ++c) s += g[c] * wv[c];
    s += __shfl_xor(s, 1);
    s += __shfl_xor(s, 2);
    s += __shfl_xor(s, 4);
    s += __shfl_xor(s, 8);
    if (g16 == 0) {
      s = ws[WS_BFC + e*2 + o] + s * (1.f/(float)PIX);
      size_t base = (size_t)2 * M_ * H_ * W_;
      if (o == 0) { ws[WS_SCALE + m] = s; out[base + m] = s; }
      else        { ws[WS_SHIFT + m] = s; out[base + M_ + m] = s; }
    }
  }
}

// ---------------- bilinear resize 14x14 -> 480x640 + affine ----------------
__global__ __launch_bounds__(256) void resize_kernel(
    const float* __restrict__ ws_c, const float* __restrict__ ws_scale,
    const float* __restrict__ ws_shift, float* __restrict__ out)
{
  __shared__ float cs[PIX];
  int bx = blockIdx.x;
  int m = bx / 150;
  int chunk = bx % 150;
  int tid = threadIdx.x;
  if (tid < PIX) cs[tid] = ws_c[m*PIX + tid];
  __syncthreads();
  float sc = ws_scale[m], sh = ws_shift[m];
  int q0 = chunk*2048 + tid*8;
  int y = q0 / W_;
  int x0i = q0 - y*W_;
  float py = ((float)y + 0.5f) * (14.f/(float)H_) - 0.5f;
  py = fminf(fmaxf(py, 0.f), 13.f);
  int y0 = (int)py; y0 = y0 > 12 ? 12 : y0;
  float wy = py - (float)y0;
  const float* r0 = cs + y0*R_;
  const float* r1 = r0 + R_;
  float vd[8], vc[8];
  #pragma unroll
  for (int u = 0; u < 8; ++u) {
    int x = x0i + u;
    float px = ((float)x + 0.5f) * (14.f/(float)W_) - 0.5f;
    px = fminf(fmaxf(px, 0.f), 13.f);
    int xq = (int)px; xq = xq > 12 ? 12 : xq;
    float wx = px - (float)xq;
    float v = (r0[xq]*(1.f-wx) + r0[xq+1]*wx) * (1.f-wy)
            + (r1[xq]*(1.f-wx) + r1[xq+1]*wx) * wy;
    vc[u] = v;
    vd[u] = fmaxf(v*sc + sh, 0.001f);
  }
  size_t base = (size_t)m * H_ * W_ + q0;
  float* od = out + base;
  float* oc = out + (size_t)M_*H_*W_ + base;
  *(float4*)(od)     = make_float4(vd[0], vd[1], vd[2], vd[3]);
  *(float4*)(od + 4) = make_float4(vd[4], vd[5], vd[6], vd[7]);
  *(float4*)(oc)     = make_float4(vc[0], vc[1], vc[2], vc[3]);
  *(float4*)(oc + 4) = make_float4(vc[4], vc[5], vc[6], vc[7]);
}

extern "C" void kernel_launch(void* const* d_in, const int* in_sizes, int n_in,
                              void* d_out, int out_size, void* d_ws, size_t ws_size,
                              hipStream_t stream) {
  const float* fmap  = (const float*)d_in[2];
  const float* boxes = (const float*)d_in[8];
  const int* labels  = (const int*)d_in[9];
  const float* w_s  = (const float*)d_in[10];
  const float* b_s  = (const float*)d_in[11];
  const float* w_fc = (const float*)d_in[12];
  const float* b_fc = (const float*)d_in[13];
  const float* w_c1 = (const float*)d_in[14];
  const float* b_c1 = (const float*)d_in[15];
  const float* w_c2 = (const float*)d_in[16];
  const float* b_c2 = (const float*)d_in[17];
  float* ws = (float*)d_ws;
  float* out = (float*)d_out;

  hipLaunchKernelGGL(prep_xb_kernel, dim3(PREP_BLK + M_), dim3(256), 0, stream,
                     fmap, boxes, w_s, b_s, w_fc, b_fc, w_c1, b_c1, w_c2, b_c2, ws);
  hipLaunchKernelGGL(gemm_kernel, dim3(M_*6), dim3(256), 0, stream,
                     labels, ws);
  hipLaunchKernelGGL(convc2_fc_kernel, dim3(M_), dim3(256), 0, stream,
                     labels, ws, out);
  hipLaunchKernelGGL(resize_kernel, dim3(M_*150), dim3(256), 0, stream,
                     ws + WS_C, ws + WS_SCALE, ws + WS_SHIFT, out);
}